// Round 10
// baseline (93.659 us; speedup 1.0000x reference)
//
#include <hip/hip_runtime.h>
#include <math.h>

// NormalLoss: for each template vertex (M=6890), take the K=15 scan points
// (N=20000) with LARGEST distance, among them pick the min-angle normal
// match, loss = mean ||sv[sel]-tv||.
//
// Round-10 design (r6/r8/r9 ledger: main is bound by per-vertex serialized
// cross-lane ops at ~40-60 cyc each on the LDS pipe):
//  * main kernel: 4 VERTICES PER WAVE in 16-lane groups (K=15 fits a group).
//    All cross-lane machinery is group-scoped (shfl_xor j<=8 stays in-group),
//    so one wave-wide op serves 4 vertices; event loops run in lockstep
//    across groups (wall = max over groups, not sum). ~3x fewer cross-lane
//    op-slots per vertex.
//  * bootstrap: sort16 + 3x(sort16+merge16) => exact sorted top-16 of the
//    first 64 points per group -> same thr quality as r6's sort64.
//  * scan: 16 points/iter/group (all groups read the same 16 float4s, L1);
//    smax break checked every 64 points (r6 semantics; a "done" group
//    produces no candidates anyway since bound < thr).
//  * 256-thread blocks (r9 showed 64-thread blocks cost +4.6us dispatch).
//  * hist -> scan_scatter -> main -> reduce; all tie-breaks explicit on
//    (d2 desc, origIdx asc) -> exact jax top_k + argmin semantics.

constexpr int K = 15;
constexpr int NBUCK = 256;

__device__ __forceinline__ int bucket_of(float k2) {
    int b = (int)(k2 * 8.0f);           // 0.125-wide buckets over |p|^2 in [0,32)
    b = b > (NBUCK - 1) ? (NBUCK - 1) : b;
    return (NBUCK - 1) - b;             // bucket 0 = largest |p|
}

__global__ __launch_bounds__(256) void hist_kernel(
    const float* __restrict__ sv, int* __restrict__ blkhist, int N)
{
    __shared__ int h[NBUCK];
    int t = threadIdx.x;
    h[t] = 0;
    __syncthreads();
    int i = blockIdx.x * 256 + t;
    if (i < N) {
        float x = sv[3*i], y = sv[3*i+1], z = sv[3*i+2];
        atomicAdd(&h[bucket_of(fmaf(x, x, fmaf(y, y, z*z)))], 1);
    }
    __syncthreads();
    blkhist[blockIdx.x * NBUCK + t] = h[t];   // full-row overwrite (poison-safe)
}

__global__ __launch_bounds__(256) void scan_scatter_kernel(
    const float* __restrict__ sv,
    const int*   __restrict__ blkhist,  // [nblk][NBUCK]
    float4*      __restrict__ sorted,   // [N] out: (x,y,z,bitcast(origIdx))
    float*       __restrict__ smax,     // [nb] out: |p| upper bound at pos >= j*64
    int N, int nb, int nblk)
{
    __shared__ int tmp[NBUCK];
    __shared__ int startSh[NBUCK];
    __shared__ int cursor[NBUCK];
    const int t   = threadIdx.x;
    const int blk = blockIdx.x;

    int mine = 0, total = 0;
#pragma unroll 8
    for (int b = 0; b < nblk; ++b) {
        int v = blkhist[b * NBUCK + t];
        if (b < blk) mine += v;
        total += v;
    }
    tmp[t] = total;
    __syncthreads();
    for (int d = 1; d < NBUCK; d <<= 1) {
        int u = (t >= d) ? tmp[t - d] : 0;
        __syncthreads();
        tmp[t] += u;
        __syncthreads();
    }
    int startv = tmp[t] - total;        // exclusive bucket start
    startSh[t] = startv;
    cursor[t]  = startv + mine;         // this block's write base per bucket
    __syncthreads();

    if (blk == 0) {
        // smax[j]: bucket-edge upper bound on |p| for positions >= j*64;
        // exact and independent of within-bucket order.
        for (int j = t; j < nb; j += 256) {
            int pos = j * 64;
            int lo = 0, hi = NBUCK - 1;
            while (lo < hi) {
                int mid = (lo + hi + 1) >> 1;
                if (startSh[mid] <= pos) lo = mid; else hi = mid - 1;
            }
            int bOrig = (NBUCK - 1) - lo;
            smax[j] = sqrtf((float)(bOrig + 1) * 0.125f);
        }
    }

    int i = blk * 256 + t;
    if (i < N) {
        float x = sv[3*i], y = sv[3*i+1], z = sv[3*i+2];
        float k2 = fmaf(x, x, fmaf(y, y, z*z));
        int pos = atomicAdd(&cursor[bucket_of(k2)], 1);   // LDS atomic
        sorted[pos] = make_float4(x, y, z, __int_as_float(i));
    }
}

// 16-lane bitonic sort within each group, descending by (v desc, idx asc).
// shfl_xor with j<=8 never crosses the 16-lane group boundary.
__device__ __forceinline__ void sort16(float& v, int& idx, int li) {
#pragma unroll
    for (int k = 2; k <= 16; k <<= 1) {
#pragma unroll
        for (int j = k >> 1; j > 0; j >>= 1) {
            float ov = __shfl_xor(v, j);
            int   oi = __shfl_xor(idx, j);
            bool up    = ((li & k) == 0);   // k=16 -> all-descending final stage
            bool lower = ((li & j) == 0);
            bool mine  = (v > ov) || (v == ov && idx < oi);
            bool keep  = lower ? (up ? mine : !mine) : (up ? !mine : mine);
            if (!keep) { v = ov; idx = oi; }
        }
    }
}

// merge sorted-desc B into sorted-desc A within a 16-lane group;
// A keeps the top-16 (sorted desc). lane^15 reverses within the group.
__device__ __forceinline__ void merge16(float& av, int& ai, float bv, int bi,
                                        int lane, int li) {
    bv = __shfl(bv, lane ^ 15);
    bi = __shfl(bi, lane ^ 15);
    {
        bool aB = (av > bv) || (av == bv && ai < bi);
        av = aB ? av : bv;
        ai = aB ? ai : bi;
    }
#pragma unroll
    for (int j = 8; j > 0; j >>= 1) {
        float ov = __shfl_xor(av, j);
        int   oi = __shfl_xor(ai, j);
        bool lower = ((li & j) == 0);
        bool mine  = (av > ov) || (av == ov && ai < oi);
        bool keep  = lower ? mine : !mine;
        if (!keep) { av = ov; ai = oi; }
    }
}

template<bool SORTED>
__global__ __launch_bounds__(256) void knn_loss_kernel(
    const float4* __restrict__ pts,   // sorted points (SORTED only)
    const float*  __restrict__ smax,  // suffix |p| upper bound per 64-block
    const float*  __restrict__ sv,    // [N,3] original scan vertices
    const float*  __restrict__ tv,    // [M,3]
    const float*  __restrict__ sn,    // [N,3]
    const float*  __restrict__ tn,    // [M,3]
    float* __restrict__ partial,      // [M] per-vertex contributions
    int N, int M, float invM)
{
    const int lane  = threadIdx.x & 63;
    const int w     = threadIdx.x >> 6;
    const int g     = lane >> 4;          // group 0..3 (one vertex each)
    const int li    = lane & 15;          // lane within group
    const int gbase = lane & ~15;         // group's base lane
    const int gsh   = g * 16;             // shift for ballot slices

    int m = blockIdx.x * 16 + w * 4 + g;
    const bool mvalid = (m < M);
    if (!mvalid) m = M - 1;               // duplicate compute, write suppressed

    const float tvx = tv[3*m], tvy = tv[3*m+1], tvz = tv[3*m+2];
    const float tlen = sqrtf(tvx*tvx + tvy*tvy + tvz*tvz);

    // ---- bootstrap: exact sorted top-16 of first 64 points (per group) ----
    float av; int ai;
    {
        int pi = li;
        int l = (pi < N) ? pi : 0;
        float px, py, pz;
        if (SORTED) {
            float4 q = pts[l];
            px = q.x; py = q.y; pz = q.z; ai = __float_as_int(q.w);
        } else {
            px = sv[3*l]; py = sv[3*l+1]; pz = sv[3*l+2]; ai = l;
        }
        float dx = px - tvx, dy = py - tvy, dz = pz - tvz;
        av = fmaf(dx, dx, fmaf(dy, dy, dz * dz));
        if (pi >= N) { av = -1.0f; ai = 0x7FFFFFFF; }
    }
    sort16(av, ai, li);
#pragma unroll
    for (int c = 1; c < 4; ++c) {
        int pi = c * 16 + li;
        int l = (pi < N) ? pi : 0;
        float bvv; int bii;
        float px, py, pz;
        if (SORTED) {
            float4 q = pts[l];
            px = q.x; py = q.y; pz = q.z; bii = __float_as_int(q.w);
        } else {
            px = sv[3*l]; py = sv[3*l+1]; pz = sv[3*l+2]; bii = l;
        }
        float dx = px - tvx, dy = py - tvy, dz = pz - tvz;
        bvv = fmaf(dx, dx, fmaf(dy, dy, dz * dz));
        if (pi >= N) { bvv = -1.0f; bii = 0x7FFFFFFF; }
        sort16(bvv, bii, li);
        merge16(av, ai, bvv, bii, lane, li);
    }
    // keep exactly K=15 entries: li 0..14 sorted desc; li 15 is sentinel
    float eV = (li < K) ? av : -1.0f;
    int   eI = (li < K) ? ai : 0x7FFFFFFF;
    float thr = __shfl(eV, gbase + (K - 1));   // group's 15th-largest d2
    bool  done = false;

    // ---- main scan: 16 points/iter/group; groups in lockstep ----
    for (int ib = 64; ib < N; ib += 16) {
        if (SORTED && (ib & 63) == 0) {
            float bnd = smax[ib >> 6] + tlen;         // d <= |p| + |tv|
            done = done || (bnd * bnd * 1.00001f < thr);
            if (__ballot(!done) == 0ull) break;       // all 4 groups done
        }
        int  i   = ib + li;
        bool has = (i < N);
        float d2; int oi2;
        if (SORTED) {
            float4 q = pts[has ? i : 0];
            float dx = q.x - tvx, dy = q.y - tvy, dz = q.z - tvz;
            d2 = fmaf(dx, dx, fmaf(dy, dy, dz * dz));
            oi2 = __float_as_int(q.w);
        } else {
            int gg = has ? i : 0;
            float dx = sv[3*gg] - tvx, dy = sv[3*gg+1] - tvy, dz = sv[3*gg+2] - tvz;
            d2 = fmaf(dx, dx, fmaf(dy, dy, dz * dz));
            oi2 = i;
        }
        // >= : an equal-d2 candidate with lower original idx must displace
        bool cand = has && (d2 >= thr);
        unsigned long long mball = __ballot(cand);
        if (mball) {
            unsigned mg = (unsigned)((mball >> gsh) & 0xFFFFull); // group slice
            while (__ballot(mg != 0u)) {
                bool act = (mg != 0u);
                int  src = act ? (gbase + (__ffs((int)mg) - 1)) : lane;
                if (act) mg &= mg - 1u;                 // pop processed bit
                float cv = __shfl(d2, src);             // per-lane src ok
                int   ci = __shfl(oi2, src);
                unsigned long long bball =
                    __ballot((eV > cv) || (eV == cv && eI < ci));
                int p = __popcll((bball >> gsh) & 0x7FFFull);
                float uv = __shfl_up(eV, 1);            // li=0 never uses it
                int   ui = __shfl_up(eI, 1);
                if (act && p < K && li < K) {
                    if (li == p)      { eV = cv; eI = ci; }
                    else if (li > p)  { eV = uv; eI = ui; }
                }
                thr = __shfl(eV, gbase + (K - 1));      // tighten per group
                unsigned long long pr = __ballot(d2 >= thr);
                mg &= (unsigned)((pr >> gsh) & 0xFFFFull);  // prune doomed
            }
        }
    }

    // ---- epilogue: per-group argmin angle, tie-break by rank (= li) ----
    const float tnx = tn[3*m], tny = tn[3*m+1], tnz = tn[3*m+2];
    float ang = 3.0e38f;
    int myI = eI;
    if (li < K && myI != 0x7FFFFFFF) {
        float dot = sn[3*myI]*tnx + sn[3*myI+1]*tny + sn[3*myI+2]*tnz;
        dot = fminf(1.0f, fmaxf(-1.0f, dot));
        ang = acosf(dot) * 57.29577951308232f;   // degrees, matches jnp
    }
    float ba = ang; int br = li; int bi = myI;
#pragma unroll
    for (int s = 1; s < 16; s <<= 1) {
        float oa  = __shfl_xor(ba, s);
        int   orr = __shfl_xor(br, s);
        int   oi  = __shfl_xor(bi, s);
        bool take = (oa < ba) || (oa == ba && orr < br);
        if (take) { ba = oa; br = orr; bi = oi; }
    }
    if (li == 0 && mvalid) {
        float dx = sv[3*bi]   - tvx;
        float dy = sv[3*bi+1] - tvy;
        float dz = sv[3*bi+2] - tvz;
        partial[m] = sqrtf(dx*dx + dy*dy + dz*dz) * invM;
    }
}

__global__ __launch_bounds__(256) void reduce_kernel(
    const float* __restrict__ partial, float* __restrict__ out, int n)
{
    __shared__ float sh[4];
    const int lane = threadIdx.x & 63;
    const int w    = threadIdx.x >> 6;
    float s = 0.0f;
    for (int i = threadIdx.x; i < n; i += 256) s += partial[i];
#pragma unroll
    for (int d = 1; d < 64; d <<= 1) s += __shfl_xor(s, d);
    if (lane == 0) sh[w] = s;
    __syncthreads();
    if (threadIdx.x == 0) out[0] = sh[0] + sh[1] + sh[2] + sh[3];
}

extern "C" void kernel_launch(void* const* d_in, const int* in_sizes, int n_in,
                              void* d_out, int out_size, void* d_ws, size_t ws_size,
                              hipStream_t stream) {
    const float* sv = (const float*)d_in[0];   // scan_vertices   [1,N,3]
    const float* tv = (const float*)d_in[1];   // template_vertices [1,M,3]
    const float* sn = (const float*)d_in[2];   // scan_normals    [N,3]
    const float* tn = (const float*)d_in[3];   // template_normals [M,3]
    // d_in[4] = K_knn (fixed 15, compile-time)

    int N = in_sizes[0] / 3;
    int M = in_sizes[1] / 3;
    int nb = (N + 63) / 64;
    float* out = (float*)d_out;
    float invM = 1.0f / (float)M;
    int nblk  = (N + 255) / 256;
    int gridM = (M + 15) / 16;   // 16 vertices per 256-thread block

    // d_ws layout: [sorted float4 x N][smax x nb][blkhist x nblk*256][partial x M]
    size_t offSorted  = 0;
    size_t offSmax    = offSorted + (size_t)N * sizeof(float4);
    size_t offHist    = (offSmax + (size_t)nb * sizeof(float) + 15) & ~(size_t)15;
    size_t offPartial = offHist + (size_t)nblk * NBUCK * sizeof(int);
    size_t need       = offPartial + (size_t)M * sizeof(float);

    if (ws_size >= need) {
        float4* sorted  = (float4*)((char*)d_ws + offSorted);
        float*  smax    = (float*) ((char*)d_ws + offSmax);
        int*    blkhist = (int*)   ((char*)d_ws + offHist);
        float*  partial = (float*) ((char*)d_ws + offPartial);

        hist_kernel        <<<nblk, 256, 0, stream>>>(sv, blkhist, N);
        scan_scatter_kernel<<<nblk, 256, 0, stream>>>(sv, blkhist, sorted,
                                                      smax, N, nb, nblk);
        knn_loss_kernel<true><<<gridM, 256, 0, stream>>>(
            sorted, smax, sv, tv, sn, tn, partial, N, M, invM);
        reduce_kernel      <<<1, 256, 0, stream>>>(partial, out, M);
    } else {
        float* partial = (float*)d_ws;
        knn_loss_kernel<false><<<gridM, 256, 0, stream>>>(
            nullptr, nullptr, sv, tv, sn, tn, partial, N, M, invM);
        reduce_kernel      <<<1, 256, 0, stream>>>(partial, out, M);
    }
}